// Round 2
// baseline (946.058 us; speedup 1.0000x reference)
//
#include <hip/hip_runtime.h>

#define H 128

typedef __bf16 bf8_t __attribute__((ext_vector_type(8)));
typedef float  f4_t  __attribute__((ext_vector_type(4)));

#define MFMA16(a, b, c) __builtin_amdgcn_mfma_f32_16x16x32_bf16((a), (b), (c), 0, 0, 0)

__device__ __forceinline__ float silu_f(float v) {
    return v * (1.0f / (1.0f + __expf(-v)));
}

// Dual-dtype scalar load (weights/biases): idx in elements.
__device__ __forceinline__ float wload(const void* p, int idx, bool f32) {
    return f32 ? ((const float*)p)[idx] : (float)((const __bf16*)p)[idx];
}

// Dual-dtype 8-element row chunk -> bf16x8
__device__ __forceinline__ bf8_t hload8(const void* p, size_t off, bool f32) {
    bf8_t v;
    if (f32) {
        const float4* q = (const float4*)((const float*)p + off);
        const float4 a = q[0], b = q[1];
        v[0]=(__bf16)a.x; v[1]=(__bf16)a.y; v[2]=(__bf16)a.z; v[3]=(__bf16)a.w;
        v[4]=(__bf16)b.x; v[5]=(__bf16)b.y; v[6]=(__bf16)b.z; v[7]=(__bf16)b.w;
    } else {
        v = *(const bf8_t*)((const __bf16*)p + off);
    }
    return v;
}

// ---------------------------------------------------------------------------
// Detect input dtypes. flags[0]=1 if float tensors are f32 (else bf16).
// flags[1]=1 if edge_index is int64 (else int32). Deterministic per input.
// ---------------------------------------------------------------------------
__global__ void detect_kernel(const unsigned short* __restrict__ hraw,
                              const int* __restrict__ eiraw, int* __restrict__ flags)
{
    __shared__ int s_nf, s_oddnz;
    if (threadIdx.x == 0) { s_nf = 0; s_oddnz = 0; }
    __syncthreads();
    int nf = 0;
    for (int i = threadIdx.x; i < 16384; i += blockDim.x) {
        const unsigned short u = hraw[i];
        if (((u >> 7) & 0xFF) == 0xFF) nf++;   // bf16 exponent all-ones => non-finite
    }
    int onz = 0;
    for (int i = threadIdx.x; i < 512; i += blockDim.x) {
        if (eiraw[2*i + 1] != 0) onz++;        // int64 high words are all zero
    }
    if (nf)  atomicAdd(&s_nf, nf);
    if (onz) atomicAdd(&s_oddnz, onz);
    __syncthreads();
    if (threadIdx.x == 0) {
        flags[0] = (s_nf > 0) ? 1 : 0;
        flags[1] = (s_oddnz == 0) ? 1 : 0;
    }
}

// Canonicalize edge_index to int32.
__global__ void cvt_ei_kernel(const void* __restrict__ src, int* __restrict__ dst,
                              int n, const int* __restrict__ flags)
{
    const int i = blockIdx.x*blockDim.x + threadIdx.x;
    if (i >= n) return;
    dst[i] = flags[1] ? (int)((const long long*)src)[i] : ((const int*)src)[i];
}

// ---------------------------------------------------------------------------
// Edge kernel: fused edge MLP over 32-edge tiles. 8 waves/block:
// wave (mg in {0,1}) x (ng in 0..3) owns rows mg*16..+15, cols ng*32..+31.
// Weight B-fragments persistent in registers.
// ---------------------------------------------------------------------------
__global__ __launch_bounds__(512, 2)
void egnn_edge_kernel(const void* __restrict__ h, const void* __restrict__ x,
                      const int* __restrict__ ei,
                      const void* __restrict__ We1, const void* __restrict__ be1,
                      const void* __restrict__ We2, const void* __restrict__ be2,
                      const void* __restrict__ Wc1, const void* __restrict__ bc1,
                      const void* __restrict__ Wc2, const int* __restrict__ flags,
                      float* __restrict__ msg_agg, float* __restrict__ coord_agg,
                      int Nn, int Ee)
{
    const bool f32 = flags[0] != 0;
    const int tid  = threadIdx.x;
    const int wv   = tid >> 6;
    const int lane = tid & 63;
    const int quad = lane >> 4;
    const int l15  = lane & 15;
    const int mg   = wv >> 2;
    const int ng   = wv & 3;

    // persistent B fragments: B[k][n], n = lane&15, k = quad*8+j
    bf8_t bW1[8][2];
    bf8_t bW2[4][2];
    bf8_t bWc[4][2];
    float be1v[2], be2v[2], bc1v[2], w1dv[2], wc2v[2];
    #pragma unroll
    for (int t = 0; t < 2; ++t) {
        const int n = ng*32 + t*16 + l15;
        #pragma unroll
        for (int kc = 0; kc < 8; ++kc) {
            bf8_t v;
            #pragma unroll
            for (int j = 0; j < 8; ++j) v[j] = (__bf16)wload(We1, (kc*32 + quad*8 + j)*H + n, f32);
            bW1[kc][t] = v;
        }
        #pragma unroll
        for (int kc = 0; kc < 4; ++kc) {
            bf8_t v, u;
            #pragma unroll
            for (int j = 0; j < 8; ++j) {
                v[j] = (__bf16)wload(We2, (kc*32 + quad*8 + j)*H + n, f32);
                u[j] = (__bf16)wload(Wc1, (kc*32 + quad*8 + j)*H + n, f32);
            }
            bW2[kc][t] = v;
            bWc[kc][t] = u;
        }
        be1v[t] = wload(be1, n, f32);
        be2v[t] = wload(be2, n, f32);
        bc1v[t] = wload(bc1, n, f32);
        w1dv[t] = wload(We1, 256*H + n, f32);   // dist_sq row of We1
        wc2v[t] = wload(Wc2, n, f32);
    }

    __shared__ __bf16 s_in[32*264];
    __shared__ __bf16 s_m1[32*136];
    __shared__ __bf16 s_m2[32*136];
    __shared__ float  s_rel[32*3];
    __shared__ float  s_dist[32];
    __shared__ int    s_dstv[32];
    __shared__ float  s_cw[32*4];

    const int tiles = Ee >> 5;
    for (int tile = blockIdx.x; tile < tiles; tile += gridDim.x) {
        const int ebase = tile << 5;
        __syncthreads();

        if (tid < 32) {
            const int e  = ebase + tid;
            const int sn = ei[e];
            const int dn = ei[Ee + e];
            s_dstv[tid] = dn;
            float d2 = 0.f;
            #pragma unroll
            for (int c = 0; c < 3; ++c) {
                float r;
                if (f32) r = ((const float*)x)[sn*3 + c] - ((const float*)x)[dn*3 + c];
                else     r = (float)((const __bf16*)x)[sn*3 + c] - (float)((const __bf16*)x)[dn*3 + c];
                s_rel[tid*3 + c] = r;
                d2 += r*r;
            }
            s_dist[tid] = d2;
        }
        #pragma unroll
        for (int r = 0; r < 2; ++r) {
            const int idx = tid + r*512;
            const int m = idx >> 5, c = idx & 31;
            const int e = ebase + m;
            const int node = (c < 16) ? ei[e] : ei[Ee + e];
            *(bf8_t*)&s_in[m*264 + c*8] = hload8(h, (size_t)node*H + (c & 15)*8, f32);
        }
        __syncthreads();

        // layer 1
        {
            f4_t a0 = {0.f,0.f,0.f,0.f}, a1 = {0.f,0.f,0.f,0.f};
            const int abase = (mg*16 + l15)*264 + quad*8;
            #pragma unroll
            for (int kc = 0; kc < 8; ++kc) {
                const bf8_t a = *(const bf8_t*)&s_in[abase + kc*32];
                a0 = MFMA16(a, bW1[kc][0], a0);
                a1 = MFMA16(a, bW1[kc][1], a1);
            }
            #pragma unroll
            for (int i = 0; i < 4; ++i) {
                const int m = mg*16 + quad*4 + i;
                const float d2 = s_dist[m];
                s_m1[m*136 + ng*32 + l15]      = (__bf16)silu_f(a0[i] + d2*w1dv[0] + be1v[0]);
                s_m1[m*136 + ng*32 + 16 + l15] = (__bf16)silu_f(a1[i] + d2*w1dv[1] + be1v[1]);
            }
        }
        __syncthreads();

        // layer 2 + msg scatter
        {
            f4_t a0 = {0.f,0.f,0.f,0.f}, a1 = {0.f,0.f,0.f,0.f};
            const int abase = (mg*16 + l15)*136 + quad*8;
            #pragma unroll
            for (int kc = 0; kc < 4; ++kc) {
                const bf8_t a = *(const bf8_t*)&s_m1[abase + kc*32];
                a0 = MFMA16(a, bW2[kc][0], a0);
                a1 = MFMA16(a, bW2[kc][1], a1);
            }
            #pragma unroll
            for (int i = 0; i < 4; ++i) {
                const int m = mg*16 + quad*4 + i;
                const float v0 = silu_f(a0[i] + be2v[0]);
                const float v1 = silu_f(a1[i] + be2v[1]);
                s_m2[m*136 + ng*32 + l15]      = (__bf16)v0;
                s_m2[m*136 + ng*32 + 16 + l15] = (__bf16)v1;
                const size_t db = (size_t)s_dstv[m]*H + ng*32 + l15;
                atomicAdd(&msg_agg[db],      v0);
                atomicAdd(&msg_agg[db + 16], v1);
            }
        }
        __syncthreads();

        // layer 3: coord head
        {
            f4_t a0 = {0.f,0.f,0.f,0.f}, a1 = {0.f,0.f,0.f,0.f};
            const int abase = (mg*16 + l15)*136 + quad*8;
            #pragma unroll
            for (int kc = 0; kc < 4; ++kc) {
                const bf8_t a = *(const bf8_t*)&s_m2[abase + kc*32];
                a0 = MFMA16(a, bWc[kc][0], a0);
                a1 = MFMA16(a, bWc[kc][1], a1);
            }
            float p[4];
            #pragma unroll
            for (int i = 0; i < 4; ++i) {
                const float v0 = silu_f(a0[i] + bc1v[0]);
                const float v1 = silu_f(a1[i] + bc1v[1]);
                p[i] = v0*wc2v[0] + v1*wc2v[1];
            }
            #pragma unroll
            for (int off = 1; off < 16; off <<= 1) {
                #pragma unroll
                for (int i = 0; i < 4; ++i) p[i] += __shfl_xor(p[i], off, 64);
            }
            if (l15 == 0) {
                #pragma unroll
                for (int i = 0; i < 4; ++i)
                    s_cw[(mg*16 + quad*4 + i)*4 + ng] = p[i];
            }
        }
        __syncthreads();

        if (tid < 96) {
            const int m = tid / 3, c = tid - m*3;
            const float cw = s_cw[m*4 + 0] + s_cw[m*4 + 1] + s_cw[m*4 + 2] + s_cw[m*4 + 3];
            atomicAdd(&coord_agg[(size_t)s_dstv[m]*3 + c], s_rel[m*3 + c]*cw);
        }
    }
}

// ---------------------------------------------------------------------------
// Node kernel: h_out = h + silu([h | msg_agg] @ Wn1 + bn1) @ Wn2 + bn2
// ---------------------------------------------------------------------------
__global__ __launch_bounds__(512, 2)
void egnn_node_kernel(const void* __restrict__ h, const float* __restrict__ msg_agg,
                      const void* __restrict__ Wn1, const void* __restrict__ bn1,
                      const void* __restrict__ Wn2, const void* __restrict__ bn2,
                      const int* __restrict__ flags, void* __restrict__ h_out, int Nn)
{
    const bool f32 = flags[0] != 0;
    const int tid  = threadIdx.x;
    const int wv   = tid >> 6;
    const int lane = tid & 63;
    const int quad = lane >> 4;
    const int l15  = lane & 15;
    const int mg   = wv >> 2;
    const int ng   = wv & 3;

    bf8_t bW1[8][2];
    bf8_t bW2[4][2];
    float b1v[2], b2v[2];
    #pragma unroll
    for (int t = 0; t < 2; ++t) {
        const int n = ng*32 + t*16 + l15;
        #pragma unroll
        for (int kc = 0; kc < 8; ++kc) {
            bf8_t v;
            #pragma unroll
            for (int j = 0; j < 8; ++j) v[j] = (__bf16)wload(Wn1, (kc*32 + quad*8 + j)*H + n, f32);
            bW1[kc][t] = v;
        }
        #pragma unroll
        for (int kc = 0; kc < 4; ++kc) {
            bf8_t v;
            #pragma unroll
            for (int j = 0; j < 8; ++j) v[j] = (__bf16)wload(Wn2, (kc*32 + quad*8 + j)*H + n, f32);
            bW2[kc][t] = v;
        }
        b1v[t] = wload(bn1, n, f32);
        b2v[t] = wload(bn2, n, f32);
    }

    __shared__ __bf16 s_in[32*264];
    __shared__ __bf16 s_t1[32*136];

    const int tiles = (Nn + 31) >> 5;
    for (int tile = blockIdx.x; tile < tiles; tile += gridDim.x) {
        const int nb = tile << 5;
        __syncthreads();
        #pragma unroll
        for (int r = 0; r < 2; ++r) {
            const int idx = tid + r*512;
            const int m = idx >> 5, c = idx & 31;
            int node = nb + m;
            if (node >= Nn) node = Nn - 1;
            if (c < 16) {
                *(bf8_t*)&s_in[m*264 + c*8] = hload8(h, (size_t)node*H + c*8, f32);
            } else {
                const float4* mp = (const float4*)(msg_agg + (size_t)node*H + (c - 16)*8);
                const float4 v0 = mp[0], v1 = mp[1];
                __bf16* d = &s_in[m*264 + c*8];
                d[0] = (__bf16)v0.x; d[1] = (__bf16)v0.y; d[2] = (__bf16)v0.z; d[3] = (__bf16)v0.w;
                d[4] = (__bf16)v1.x; d[5] = (__bf16)v1.y; d[6] = (__bf16)v1.z; d[7] = (__bf16)v1.w;
            }
        }
        __syncthreads();

        {
            f4_t a0 = {0.f,0.f,0.f,0.f}, a1 = {0.f,0.f,0.f,0.f};
            const int abase = (mg*16 + l15)*264 + quad*8;
            #pragma unroll
            for (int kc = 0; kc < 8; ++kc) {
                const bf8_t a = *(const bf8_t*)&s_in[abase + kc*32];
                a0 = MFMA16(a, bW1[kc][0], a0);
                a1 = MFMA16(a, bW1[kc][1], a1);
            }
            #pragma unroll
            for (int i = 0; i < 4; ++i) {
                const int m = mg*16 + quad*4 + i;
                s_t1[m*136 + ng*32 + l15]      = (__bf16)silu_f(a0[i] + b1v[0]);
                s_t1[m*136 + ng*32 + 16 + l15] = (__bf16)silu_f(a1[i] + b1v[1]);
            }
        }
        __syncthreads();

        {
            f4_t a0 = {0.f,0.f,0.f,0.f}, a1 = {0.f,0.f,0.f,0.f};
            const int abase = (mg*16 + l15)*136 + quad*8;
            #pragma unroll
            for (int kc = 0; kc < 4; ++kc) {
                const bf8_t a = *(const bf8_t*)&s_t1[abase + kc*32];
                a0 = MFMA16(a, bW2[kc][0], a0);
                a1 = MFMA16(a, bW2[kc][1], a1);
            }
            #pragma unroll
            for (int i = 0; i < 4; ++i) {
                const int node = nb + mg*16 + quad*4 + i;
                if (node < Nn) {
                    const int n0 = ng*32 + l15, n1 = n0 + 16;
                    const size_t i0 = (size_t)node*H + n0, i1 = (size_t)node*H + n1;
                    const float h0 = f32 ? ((const float*)h)[i0] : (float)((const __bf16*)h)[i0];
                    const float h1 = f32 ? ((const float*)h)[i1] : (float)((const __bf16*)h)[i1];
                    const float o0 = a0[i] + b2v[0] + h0;
                    const float o1 = a1[i] + b2v[1] + h1;
                    if (f32) {
                        ((float*)h_out)[i0] = o0;
                        ((float*)h_out)[i1] = o1;
                    } else {
                        ((__bf16*)h_out)[i0] = (__bf16)o0;
                        ((__bf16*)h_out)[i1] = (__bf16)o1;
                    }
                }
            }
        }
    }
}

// ---------------------------------------------------------------------------
// x_out = x + coord_agg  (element index base = Nn*H in the flat output)
// ---------------------------------------------------------------------------
__global__ void egnn_x_kernel(const void* __restrict__ x, const float* __restrict__ coord_agg,
                              const int* __restrict__ flags, void* __restrict__ out,
                              size_t obase, int total)
{
    const bool f32 = flags[0] != 0;
    const int i = blockIdx.x*blockDim.x + threadIdx.x;
    if (i >= total) return;
    const float xv = f32 ? ((const float*)x)[i] : (float)((const __bf16*)x)[i];
    const float o = xv + coord_agg[i];
    if (f32) ((float*)out)[obase + i] = o;
    else     ((__bf16*)out)[obase + i] = (__bf16)o;
}

extern "C" void kernel_launch(void* const* d_in, const int* in_sizes, int n_in,
                              void* d_out, int out_size, void* d_ws, size_t ws_size,
                              hipStream_t stream)
{
    const void* h   = d_in[0];
    const void* x   = d_in[1];
    const void* ei0 = d_in[2];
    const void* We1 = d_in[3];
    const void* be1 = d_in[4];
    const void* We2 = d_in[5];
    const void* be2 = d_in[6];
    const void* Wc1 = d_in[7];
    const void* bc1 = d_in[8];
    const void* Wc2 = d_in[9];
    const void* Wn1 = d_in[10];
    const void* bn1 = d_in[11];
    const void* Wn2 = d_in[12];
    const void* bn2 = d_in[13];

    const int Nn = in_sizes[0] / H;   // 50000
    const int Ee = in_sizes[2] / 2;   // 640000

    char* ws = (char*)d_ws;
    float* msg_agg   = (float*)ws;                                        // Nn*H f32
    float* coord_agg = (float*)(ws + (size_t)Nn*H*4);                     // Nn*3 f32
    int*   ei        = (int*)  (ws + (size_t)Nn*H*4 + (size_t)Nn*3*4);    // 2*Ee i32
    int*   flags     = (int*)  (ws + (size_t)Nn*H*4 + (size_t)Nn*3*4 + (size_t)2*Ee*4);

    detect_kernel<<<1, 256, 0, stream>>>((const unsigned short*)h, (const int*)ei0, flags);
    cvt_ei_kernel<<<(2*Ee + 255)/256, 256, 0, stream>>>(ei0, ei, 2*Ee, flags);

    hipMemsetAsync(msg_agg,   0, (size_t)Nn*H*sizeof(float), stream);
    hipMemsetAsync(coord_agg, 0, (size_t)Nn*3*sizeof(float), stream);

    egnn_edge_kernel<<<1024, 512, 0, stream>>>(h, x, ei, We1, be1, We2, be2,
                                               Wc1, bc1, Wc2, flags,
                                               msg_agg, coord_agg, Nn, Ee);
    egnn_node_kernel<<<512, 512, 0, stream>>>(h, msg_agg, Wn1, bn1, Wn2, bn2,
                                              flags, d_out, Nn);
    egnn_x_kernel<<<(Nn*3 + 255)/256, 256, 0, stream>>>(x, coord_agg, flags, d_out,
                                                        (size_t)Nn*H, Nn*3);
}